// Round 1
// baseline (10057.680 us; speedup 1.0000x reference)
//
#include <hip/hip_runtime.h>
#include <cstddef>

// ---------------------------------------------------------------------------
// AttentionalGNN (SuperGlue-style): 3 x (GAT, self-attn, cross-attn)
// B=8, D=256, NQ=4096, N3=2048, N1=16384, heads=4, dim=64
// Round 1: correctness-first fp32 implementation.
// ---------------------------------------------------------------------------

#define NQ 4096
#define N3 4096/2        // 2048
#define N1 16384
#define BATCH 8
#define KVS 16           // split-M for KV partials

// ---------------------------------------------------------------------------
// conv1x1: out[b,o,n] (or out[b,n,o] if outTrans) =
//   bias[o] + sum_c W(o,c) * in(b,c,n)
// W(o,c) = wTrans ? W[c*O+o] : W[o*C+c]
// input channel c: c < CA -> inA, else inB (for concat(x,msg) m1 conv)
// Tiling: 64(O) x 64(N) block tile, 256 threads, 4x4 per thread, K-tile 16.
// ---------------------------------------------------------------------------
__global__ __launch_bounds__(256) void conv1x1_kernel(
    const float* __restrict__ inA, int CA,
    const float* __restrict__ inB, int CB,
    const float* __restrict__ W, int wTrans,
    const float* __restrict__ bias,
    float* __restrict__ out, int outTrans,
    int O, int N)
{
    const int b  = blockIdx.z;
    const int o0 = blockIdx.y * 64;
    const int n0 = blockIdx.x * 64;
    const int C  = CA + CB;
    const int tid = threadIdx.x;
    const int ty = tid >> 4;      // 0..15 -> O sub-tile
    const int tx = tid & 15;      // 0..15 -> N sub-tile

    __shared__ float Ws[16][64];  // [k][o]
    __shared__ float Xs[16][64];  // [k][n]

    float acc[4][4] = {};

    for (int c0 = 0; c0 < C; c0 += 16) {
        // --- load W tile ---
        #pragma unroll
        for (int i = 0; i < 4; ++i) {
            int e = tid + i * 256;
            if (!wTrans) {
                int k = e & 15, o = e >> 4;
                Ws[k][o] = W[(size_t)(o0 + o) * C + (c0 + k)];
            } else {
                int o = e & 63, k = e >> 6;
                Ws[k][o] = W[(size_t)(c0 + k) * O + (o0 + o)];
            }
        }
        // --- load X tile ---
        #pragma unroll
        for (int i = 0; i < 4; ++i) {
            int e = tid + i * 256;
            int n = e & 63, k = e >> 6;
            int c = c0 + k;
            float v;
            if (c < CA) v = inA[((size_t)b * CA + c) * N + (n0 + n)];
            else        v = inB[((size_t)b * CB + (c - CA)) * N + (n0 + n)];
            Xs[k][n] = v;
        }
        __syncthreads();
        #pragma unroll
        for (int kk = 0; kk < 16; ++kk) {
            float a_[4], b_[4];
            #pragma unroll
            for (int i = 0; i < 4; ++i) a_[i] = Ws[kk][ty * 4 + i];
            #pragma unroll
            for (int j = 0; j < 4; ++j) b_[j] = Xs[kk][tx * 4 + j];
            #pragma unroll
            for (int i = 0; i < 4; ++i)
                #pragma unroll
                for (int j = 0; j < 4; ++j)
                    acc[i][j] += a_[i] * b_[j];
        }
        __syncthreads();
    }

    #pragma unroll
    for (int i = 0; i < 4; ++i) {
        int og = o0 + ty * 4 + i;
        float bv = bias ? bias[og] : 0.0f;
        #pragma unroll
        for (int j = 0; j < 4; ++j) {
            int ng = n0 + tx * 4 + j;
            float v = acc[i][j] + bv;
            if (!outTrans) out[((size_t)b * O + og) * N + ng] = v;
            else           out[((size_t)b * N + ng) * O + og] = v;
        }
    }
}

// ---------------------------------------------------------------------------
// Instance norm over last axis + ReLU, in place.  One block per (b,c) row.
// ---------------------------------------------------------------------------
__global__ __launch_bounds__(256) void instnorm_relu_kernel(
    float* __restrict__ x, int N)
{
    const size_t base = (size_t)blockIdx.x * N;
    float s = 0.f, s2 = 0.f;
    for (int i = threadIdx.x; i < N; i += 256) {
        float v = x[base + i];
        s += v; s2 += v * v;
    }
    #pragma unroll
    for (int off = 32; off; off >>= 1) {
        s  += __shfl_down(s, off, 64);
        s2 += __shfl_down(s2, off, 64);
    }
    __shared__ float rs[4], rs2[4];
    int wid = threadIdx.x >> 6;
    if ((threadIdx.x & 63) == 0) { rs[wid] = s; rs2[wid] = s2; }
    __syncthreads();
    __shared__ float smean, srstd;
    if (threadIdx.x == 0) {
        float S = rs[0] + rs[1] + rs[2] + rs[3];
        float S2 = rs2[0] + rs2[1] + rs2[2] + rs2[3];
        float m = S / N;
        float var = S2 / N - m * m;
        smean = m;
        srstd = rsqrtf(var + 1e-5f);
    }
    __syncthreads();
    float m = smean, r = srstd;
    for (int i = threadIdx.x; i < N; i += 256) {
        float v = (x[base + i] - m) * r;
        x[base + i] = v > 0.f ? v : 0.f;
    }
}

// ---------------------------------------------------------------------------
// Linear attention stage 1: partial KV[d][q] and ksum[d] over an M-chunk.
// q,k channel mapping: chan = d*4 + h (reshape (B,256,M)->(B,64,4,M))
// k gets elu(k)+1 applied; v raw (the /m ... *m pair cancels and is dropped).
// grid (KVS, H=4, B), 256 threads.
// ---------------------------------------------------------------------------
__global__ __launch_bounds__(256) void kv_partial_kernel(
    const float* __restrict__ kc, const float* __restrict__ vc,
    float* __restrict__ part, int M)
{
    const int s = blockIdx.x, h = blockIdx.y, b = blockIdx.z;
    const int chunk = M / KVS;
    const int m_begin = s * chunk;
    const int tid = threadIdx.x;
    const int ty = tid >> 4;   // d group
    const int tx = tid & 15;   // q group

    __shared__ float ke[64][65];
    __shared__ float ve[64][65];

    float acc[4][4] = {};
    float ksacc = 0.f;

    for (int mt = 0; mt < chunk; mt += 64) {
        #pragma unroll
        for (int i = 0; i < 16; ++i) {
            int e = tid + i * 256;
            int m = e & 63, d = e >> 6;
            size_t idx = ((size_t)b * 256 + d * 4 + h) * M + m_begin + mt + m;
            float kval = kc[idx];
            ke[d][m] = kval > 0.f ? kval + 1.0f : expf(kval);
            ve[d][m] = vc[idx];
        }
        __syncthreads();
        for (int mm = 0; mm < 64; ++mm) {
            float a_[4], b_[4];
            #pragma unroll
            for (int i = 0; i < 4; ++i) a_[i] = ke[ty * 4 + i][mm];
            #pragma unroll
            for (int j = 0; j < 4; ++j) b_[j] = ve[tx * 4 + j][mm];
            #pragma unroll
            for (int i = 0; i < 4; ++i)
                #pragma unroll
                for (int j = 0; j < 4; ++j)
                    acc[i][j] += a_[i] * b_[j];
        }
        if (tid < 64) {
            float t = 0.f;
            for (int mm = 0; mm < 64; ++mm) t += ke[tid][mm];
            ksacc += t;
        }
        __syncthreads();
    }

    float* pb_ = part + (size_t)((b * 4 + h) * KVS + s) * 4160;
    #pragma unroll
    for (int i = 0; i < 4; ++i)
        #pragma unroll
        for (int j = 0; j < 4; ++j)
            pb_[(ty * 4 + i) * 64 + tx * 4 + j] = acc[i][j];
    if (tid < 64) pb_[4096 + tid] = ksacc;
}

// reduce KVS partials -> KV[b,h][d*64+q], ksum[b,h][d].  grid (B*H)
__global__ __launch_bounds__(256) void kv_reduce_kernel(
    const float* __restrict__ part, float* __restrict__ KV,
    float* __restrict__ ks)
{
    const int bh = blockIdx.x;
    const float* p0 = part + (size_t)bh * KVS * 4160;
    for (int idx = threadIdx.x; idx < 4096; idx += 256) {
        float t = 0.f;
        for (int s = 0; s < KVS; ++s) t += p0[(size_t)s * 4160 + idx];
        KV[(size_t)bh * 4096 + idx] = t;
    }
    if (threadIdx.x < 64) {
        float t = 0.f;
        for (int s = 0; s < KVS; ++s) t += p0[(size_t)s * 4160 + 4096 + threadIdx.x];
        ks[bh * 64 + threadIdx.x] = t;
    }
}

// ---------------------------------------------------------------------------
// Linear attention stage 2: out[b, q*4+h, m] = Z[m] * sum_d qe[d,m]*KV[d][q]
//   qe = elu(q)+1;  Z = 1/(sum_d qe[d,m]*ksum[d] + 1e-6)
// grid (N/64, H, B), 256 threads.
// ---------------------------------------------------------------------------
__global__ __launch_bounds__(256) void attn_apply_kernel(
    const float* __restrict__ qc, const float* __restrict__ KV,
    const float* __restrict__ ksum, float* __restrict__ out, int N)
{
    const int h = blockIdx.y, b = blockIdx.z;
    const int m0 = blockIdx.x * 64;
    const int bh = b * 4 + h;
    const int tid = threadIdx.x;

    __shared__ float kvl[64][65];  // [d][q]
    __shared__ float qe[64][65];   // [d][m]
    __shared__ float ksl[64];

    #pragma unroll
    for (int i = 0; i < 16; ++i) {
        int e = tid + i * 256;
        int q = e & 63, d = e >> 6;
        kvl[d][q] = KV[(size_t)bh * 4096 + d * 64 + q];
    }
    if (tid < 64) ksl[tid] = ksum[bh * 64 + tid];
    #pragma unroll
    for (int i = 0; i < 16; ++i) {
        int e = tid + i * 256;
        int m = e & 63, d = e >> 6;
        float v = qc[((size_t)b * 256 + d * 4 + h) * N + m0 + m];
        qe[d][m] = v > 0.f ? v + 1.0f : expf(v);
    }
    __syncthreads();

    const int m = tid & 63;
    const int qg = tid >> 6;  // wave id -> q group of 16

    float den = 0.f;
    for (int d = 0; d < 64; ++d) den += qe[d][m] * ksl[d];
    float Z = 1.0f / (den + 1e-6f);

    for (int qi = 0; qi < 16; ++qi) {
        int q = qg * 16 + qi;
        float v = 0.f;
        for (int d = 0; d < 64; ++d) v += qe[d][m] * kvl[d][q];
        out[((size_t)b * 256 + q * 4 + h) * N + m0 + m] = v * Z;
    }
}

// ---------------------------------------------------------------------------
// GAT fused scoring + aggregation.  One block per (b, n) node, 256 threads.
// rows[0] = Wh3 row (from d3), rows[1..8] = Wh2 rows (leaf descriptors).
// e_l = leaky_relu(dot(rows[0],a1) + dot(rows[l],a2)); softmax over 9;
// h = sum_l attn_l * rows[l]; out = elu(h), written channel-major.
// ---------------------------------------------------------------------------
__global__ __launch_bounds__(256) void gat_fuse_kernel(
    const float* __restrict__ Wh3t, const float* __restrict__ Wh2t,
    const float* __restrict__ avec, float* __restrict__ d3out,
    int n3, int n1)
{
    const int n = blockIdx.x, b = blockIdx.y;
    const int tid = threadIdx.x;

    __shared__ float rows[9][256];
    __shared__ float redbuf[4];
    __shared__ float scores[10];
    __shared__ float attn[9];

    rows[0][tid] = Wh3t[((size_t)b * n3 + n) * 256 + tid];
    #pragma unroll
    for (int l = 1; l < 9; ++l)
        rows[l][tid] = Wh2t[((size_t)b * n1 + n * 8 + (l - 1)) * 256 + tid];
    __syncthreads();

    const float a1v = avec[tid];
    const float a2v = avec[256 + tid];

    for (int idx = 0; idx < 10; ++idx) {
        float p = (idx == 0) ? rows[0][tid] * a1v : rows[idx - 1][tid] * a2v;
        #pragma unroll
        for (int off = 32; off; off >>= 1) p += __shfl_down(p, off, 64);
        if ((tid & 63) == 0) redbuf[tid >> 6] = p;
        __syncthreads();
        if (tid == 0) scores[idx] = redbuf[0] + redbuf[1] + redbuf[2] + redbuf[3];
        __syncthreads();
    }

    if (tid == 0) {
        float s3 = scores[0];
        float e[9], mx = -1e30f;
        #pragma unroll
        for (int l = 0; l < 9; ++l) {
            float t = s3 + scores[l + 1];
            t = t > 0.f ? t : 0.2f * t;   // leaky_relu alpha=0.2
            e[l] = t; mx = fmaxf(mx, t);
        }
        float sum = 0.f;
        #pragma unroll
        for (int l = 0; l < 9; ++l) { e[l] = expf(e[l] - mx); sum += e[l]; }
        #pragma unroll
        for (int l = 0; l < 9; ++l) attn[l] = e[l] / sum;
    }
    __syncthreads();

    float hv = 0.f;
    #pragma unroll
    for (int l = 0; l < 9; ++l) hv += attn[l] * rows[l][tid];
    hv = hv > 0.f ? hv : expf(hv) - 1.0f;   // elu
    d3out[((size_t)b * 256 + tid) * n3 + n] = hv;
}

// dst[i] += src[i]
__global__ __launch_bounds__(256) void add_kernel(
    float* __restrict__ dst, const float* __restrict__ src, size_t n)
{
    size_t i = (size_t)blockIdx.x * 256 + threadIdx.x;
    size_t stride = (size_t)gridDim.x * 256;
    for (; i < n; i += stride) dst[i] += src[i];
}

// ---------------------------------------------------------------------------
// host-side orchestration
// ---------------------------------------------------------------------------
static void conv1x1(hipStream_t s,
                    const float* inA, int CA, const float* inB, int CB,
                    const float* W, int wTrans, const float* bias,
                    float* out, int outTrans, int O, int N)
{
    dim3 g(N / 64, O / 64, BATCH), blk(256);
    conv1x1_kernel<<<g, blk, 0, s>>>(inA, CA, inB, CB, W, wTrans, bias,
                                     out, outTrans, O, N);
}

struct Ws {
    float *Qb, *Kb, *Vb, *Ab, *Mb, *Hb, *D0, *D1, *kvp, *KVb, *ksb;
};

static void attn_prop(hipStream_t s, const Ws& w,
                      const float* x, int N, const float* src, int M,
                      const float* pw, const float* pb,
                      const float* mw, const float* mb,
                      const float* m1w, const float* m1b,
                      const float* m2w, const float* m2b,
                      float* delta)
{
    // q,k,v projections
    conv1x1(s, x,   256, nullptr, 0, pw,             0, pb,        w.Qb, 0, 256, N);
    conv1x1(s, src, 256, nullptr, 0, pw + 65536,     0, pb + 256,  w.Kb, 0, 256, M);
    conv1x1(s, src, 256, nullptr, 0, pw + 2 * 65536, 0, pb + 512,  w.Vb, 0, 256, M);
    // linear attention
    kv_partial_kernel<<<dim3(KVS, 4, BATCH), 256, 0, s>>>(w.Kb, w.Vb, w.kvp, M);
    kv_reduce_kernel<<<BATCH * 4, 256, 0, s>>>(w.kvp, w.KVb, w.ksb);
    attn_apply_kernel<<<dim3(N / 64, 4, BATCH), 256, 0, s>>>(w.Qb, w.KVb, w.ksb, w.Ab, N);
    // merge conv
    conv1x1(s, w.Ab, 256, nullptr, 0, mw, 0, mb, w.Mb, 0, 256, N);
    // mlp: conv(concat(x,msg)) -> IN -> relu -> conv
    conv1x1(s, x, 256, w.Mb, 256, m1w, 0, m1b, w.Hb, 0, 512, N);
    instnorm_relu_kernel<<<BATCH * 512, 256, 0, s>>>(w.Hb, N);
    conv1x1(s, w.Hb, 512, nullptr, 0, m2w, 0, m2b, delta, 0, 256, N);
}

extern "C" void kernel_launch(void* const* d_in, const int* in_sizes, int n_in,
                              void* d_out, int out_size, void* d_ws, size_t ws_size,
                              hipStream_t stream)
{
    const float* in_q   = (const float*)d_in[0];   // (8,256,4096)
    const float* in_d3  = (const float*)d_in[1];   // (8,256,2048)
    const float* in_d2  = (const float*)d_in[2];   // (8,256,16384)
    const float* gat_W  = (const float*)d_in[3];   // (3,256,256)
    const float* gat_a  = (const float*)d_in[4];   // (3,512,1)
    const float* pw     = (const float*)d_in[5];   // (6,3,256,256)
    const float* pb     = (const float*)d_in[6];   // (6,3,256)
    const float* mw     = (const float*)d_in[7];   // (6,256,256)
    const float* mb     = (const float*)d_in[8];   // (6,256)
    const float* m1w    = (const float*)d_in[9];   // (6,512,512)
    const float* m1b    = (const float*)d_in[10];  // (6,512)
    const float* m2w    = (const float*)d_in[11];  // (6,256,512)
    const float* m2b    = (const float*)d_in[12];  // (6,256)

    const size_t SZ_Q  = (size_t)BATCH * 256 * NQ;   // 8,388,608
    const size_t SZ_D3 = (size_t)BATCH * 256 * N3;   // 4,194,304
    const size_t SZ_H  = (size_t)BATCH * 512 * NQ;   // 16,777,216

    float* P_Q  = (float*)d_out;          // persistent query state
    float* P_D3 = P_Q + SZ_Q;             // persistent d3 state

    float* w = (float*)d_ws;
    Ws ws;
    size_t off = 0;
    ws.Qb  = w + off; off += SZ_Q;
    ws.Kb  = w + off; off += SZ_Q;
    ws.Vb  = w + off; off += SZ_Q;
    ws.Ab  = w + off; off += SZ_Q;
    ws.Mb  = w + off; off += SZ_Q;
    ws.Hb  = w + off; off += SZ_H;
    ws.D0  = w + off; off += SZ_Q;
    ws.D1  = w + off; off += SZ_D3;
    ws.kvp = w + off; off += (size_t)BATCH * 4 * KVS * 4160;
    ws.KVb = w + off; off += (size_t)BATCH * 4 * 4096;
    ws.ksb = w + off; off += (size_t)BATCH * 4 * 64;
    // total ~294 MB; GAT overlays: Wh2t on Qb..Ab region, Wh3t on Hb.
    float* Wh2t = ws.Qb;   // (B, 16384, 256) = 33.5M floats
    float* Wh3t = ws.Hb;   // (B, 2048, 256)

    // init states
    hipMemcpyAsync(P_Q,  in_q,  SZ_Q  * sizeof(float), hipMemcpyDeviceToDevice, stream);
    hipMemcpyAsync(P_D3, in_d3, SZ_D3 * sizeof(float), hipMemcpyDeviceToDevice, stream);

    int gi = 0, ai = 0;
    for (int L = 0; L < 9; ++L) {
        int kind = L % 3;  // 0=GAT, 1=self, 2=cross
        if (kind == 0) {
            const float* Wg = gat_W + (size_t)gi * 65536;
            const float* ag = gat_a + (size_t)gi * 512;
            // Wh2 = desc2d_db^T leafs @ W  (transposed weight, transposed out)
            conv1x1(stream, in_d2, 256, nullptr, 0, Wg, 1, nullptr, Wh2t, 1, 256, N1);
            // Wh3 = d3^T @ W
            conv1x1(stream, P_D3, 256, nullptr, 0, Wg, 1, nullptr, Wh3t, 1, 256, N3);
            gat_fuse_kernel<<<dim3(N3, BATCH), 256, 0, stream>>>(Wh3t, Wh2t, ag, P_D3, N3, N1);
            gi++;
        } else {
            bool cross = (kind == 2);
            const float* pwi  = pw  + (size_t)ai * 3 * 65536;
            const float* pbi  = pb  + (size_t)ai * 3 * 256;
            const float* mwi  = mw  + (size_t)ai * 65536;
            const float* mbi  = mb  + (size_t)ai * 256;
            const float* m1wi = m1w + (size_t)ai * 262144;
            const float* m1bi = m1b + (size_t)ai * 512;
            const float* m2wi = m2w + (size_t)ai * 131072;
            const float* m2bi = m2b + (size_t)ai * 256;

            // delta0: x = query, src = (cross ? d3 : query)
            attn_prop(stream, ws, P_Q, NQ,
                      cross ? (const float*)P_D3 : (const float*)P_Q,
                      cross ? N3 : NQ,
                      pwi, pbi, mwi, mbi, m1wi, m1bi, m2wi, m2bi, ws.D0);
            // delta1: x = d3, src = (cross ? query : d3)
            attn_prop(stream, ws, P_D3, N3,
                      cross ? (const float*)P_Q : (const float*)P_D3,
                      cross ? NQ : N3,
                      pwi, pbi, mwi, mbi, m1wi, m1bi, m2wi, m2bi, ws.D1);
            // apply residuals (after both deltas computed)
            add_kernel<<<2048, 256, 0, stream>>>(P_Q,  ws.D0, SZ_Q);
            add_kernel<<<2048, 256, 0, stream>>>(P_D3, ws.D1, SZ_D3);
            ai++;
        }
    }
    (void)in_sizes; (void)n_in; (void)out_size; (void)ws_size;
}

// Round 2
// 3630.577 us; speedup vs baseline: 2.7703x; 2.7703x over previous
//
#include <hip/hip_runtime.h>
#include <cstddef>
#include <cstdint>

// ---------------------------------------------------------------------------
// AttentionalGNN: 3 x (GAT, self-attn, cross-attn)
// B=8, D=256, NQ=4096, N3=2048, N1=16384, heads=4, dim=64
// Round 2: bf16 MFMA GEMMs (m97 structure + XOR swizzle), fused epilogues.
// ---------------------------------------------------------------------------

#define NQ 4096
#define N3C 2048
#define N1 16384
#define BATCH 8
#define KVS 16

typedef __attribute__((ext_vector_type(8))) short bf16x8;
typedef __attribute__((ext_vector_type(4))) float f32x4;

__device__ __forceinline__ unsigned short f2bf(float f) {
    union { float f; unsigned u; } v; v.f = f;
    unsigned r = v.u + 0x7fffu + ((v.u >> 16) & 1u);
    return (unsigned short)(r >> 16);
}
__device__ __forceinline__ float bf2f(unsigned short h) {
    union { unsigned u; float f; } v; v.u = ((unsigned)h) << 16; return v.f;
}

__device__ __forceinline__ void gload_lds16(const void* g, void* l) {
    __builtin_amdgcn_global_load_lds(
        (const __attribute__((address_space(1))) unsigned int*)g,
        (__attribute__((address_space(3))) unsigned int*)l, 16, 0, 0);
}

#define OM_F32N     0
#define OM_BF16T    1
#define OM_F32T     2
#define OM_F32N_ACC 3

// ---------------------------------------------------------------------------
// MFMA GEMM: out(o,n) = bias[o] + sum_c W[o][c] * X[n][c]   (per batch b)
// W: bf16 [O][C] row-major.  X: bf16 [B][N][C] (transposed activations).
// Dual source: channel c<CA from XA, else XB (both [N][*]).
// 128x128 block tile, 4 waves (2x2, each 64x64 = 4x4 frags), BK=32.
// LDS staged via global_load_lds(16B) with kgrp^=(row&3) swizzle.
// ---------------------------------------------------------------------------
__global__ __launch_bounds__(256) void conv_mfma_kernel(
    const unsigned short* __restrict__ W,
    const unsigned short* __restrict__ XA, int CA,
    const unsigned short* __restrict__ XB,
    int C,
    const float* __restrict__ bias,
    float* __restrict__ outF,
    unsigned short* __restrict__ outT,
    int outMode, int O, int N)
{
    const int b  = blockIdx.z;
    const int o0 = blockIdx.y * 128;
    const int n0 = blockIdx.x * 128;
    const int tid = threadIdx.x;
    const int wid = tid >> 6, lane = tid & 63;
    const int wr = wid >> 1, wc = wid & 1;
    const int lr = lane & 15, kg = lane >> 4;
    const int CB = C - CA;

    __shared__ short As[128 * 32];
    __shared__ short Bs[128 * 32];

    f32x4 acc[4][4] = {};

    for (int c0 = 0; c0 < C; c0 += 32) {
        #pragma unroll
        for (int it = 0; it < 2; ++it) {
            int chunk = it * 256 + tid;
            int row = chunk >> 2;
            int ksw = (chunk & 3) ^ (row & 3);
            gload_lds16(W + (size_t)(o0 + row) * C + c0 + ksw * 8,
                        (char*)As + it * 4096 + wid * 1024);
        }
        #pragma unroll
        for (int it = 0; it < 2; ++it) {
            int chunk = it * 256 + tid;
            int row = chunk >> 2;
            int ksw = (chunk & 3) ^ (row & 3);
            int cc = c0 + ksw * 8;
            const unsigned short* src =
                (cc < CA) ? XA + ((size_t)b * N + n0 + row) * CA + cc
                          : XB + ((size_t)b * N + n0 + row) * CB + (cc - CA);
            gload_lds16(src, (char*)Bs + it * 4096 + wid * 1024);
        }
        __syncthreads();

        bf16x8 af[4], bfr[4];
        #pragma unroll
        for (int m = 0; m < 4; ++m) {
            int row = wr * 64 + m * 16 + lr;
            af[m] = *(const bf16x8*)((const char*)As + row * 64 + ((kg ^ (row & 3)) * 16));
        }
        #pragma unroll
        for (int n = 0; n < 4; ++n) {
            int row = wc * 64 + n * 16 + lr;
            bfr[n] = *(const bf16x8*)((const char*)Bs + row * 64 + ((kg ^ (row & 3)) * 16));
        }
        #pragma unroll
        for (int m = 0; m < 4; ++m)
            #pragma unroll
            for (int n = 0; n < 4; ++n)
                acc[m][n] = __builtin_amdgcn_mfma_f32_16x16x32_bf16(
                    af[m], bfr[n], acc[m][n], 0, 0, 0);
        __syncthreads();
    }

    // epilogue.  C/D frag: col = lane&15, row = (lane>>4)*4 + r  [m89]
    #pragma unroll
    for (int m = 0; m < 4; ++m) {
        const int ob = o0 + wr * 64 + m * 16 + (lane >> 4) * 4;
        float bv[4] = {0.f, 0.f, 0.f, 0.f};
        if (bias) {
            #pragma unroll
            for (int r = 0; r < 4; ++r) bv[r] = bias[ob + r];
        }
        #pragma unroll
        for (int n = 0; n < 4; ++n) {
            const int col = n0 + wc * 64 + n * 16 + lr;
            f32x4 v = acc[m][n];
            #pragma unroll
            for (int r = 0; r < 4; ++r) v[r] += bv[r];
            if (outMode == OM_F32N) {
                #pragma unroll
                for (int r = 0; r < 4; ++r)
                    outF[((size_t)b * O + ob + r) * N + col] = v[r];
            } else if (outMode == OM_F32N_ACC) {
                #pragma unroll
                for (int r = 0; r < 4; ++r)
                    outF[((size_t)b * O + ob + r) * N + col] += v[r];
            } else if (outMode == OM_F32T) {
                *(f32x4*)(outF + ((size_t)b * N + col) * O + ob) = v;
            } else {  // OM_BF16T
                unsigned p0 = ((unsigned)f2bf(v[1]) << 16) | f2bf(v[0]);
                unsigned p1 = ((unsigned)f2bf(v[3]) << 16) | f2bf(v[2]);
                *(uint2*)(outT + ((size_t)b * N + col) * O + ob) = make_uint2(p0, p1);
            }
        }
    }
}

// ---------------------------------------------------------------------------
// fp32 -> bf16 transpose-convert: in [B][C][N] -> out [B][N][C]
// ---------------------------------------------------------------------------
__global__ __launch_bounds__(256) void tcvt_kernel(
    const float* __restrict__ in, unsigned short* __restrict__ out,
    int C, int N)
{
    int b = blockIdx.z;
    int n0 = blockIdx.x * 64, c0 = blockIdx.y * 64;
    __shared__ float t[64][65];
    int a = threadIdx.x & 63, q = threadIdx.x >> 6;
    for (int i = q; i < 64; i += 4)
        t[i][a] = in[((size_t)b * C + c0 + i) * N + n0 + a];
    __syncthreads();
    for (int i = q; i < 64; i += 4)
        out[((size_t)b * N + n0 + i) * C + c0 + a] = f2bf(t[a][i]);
}

// plain fp32 -> bf16
__global__ __launch_bounds__(256) void cvt_bf16_kernel(
    const float* __restrict__ in, unsigned short* __restrict__ out, size_t n)
{
    size_t i = (size_t)blockIdx.x * 256 + threadIdx.x;
    size_t stride = (size_t)gridDim.x * 256;
    for (; i < n; i += stride) out[i] = f2bf(in[i]);
}

// gat_W [g][d][e] -> bf16 W^T [g][e][d]   (grid (4,4,3))
__global__ __launch_bounds__(256) void wtrans_cvt_kernel(
    const float* __restrict__ in, unsigned short* __restrict__ out)
{
    int g = blockIdx.z;
    int e0 = blockIdx.x * 64, d0 = blockIdx.y * 64;
    __shared__ float t[64][65];
    int a = threadIdx.x & 63, q = threadIdx.x >> 6;
    for (int i = q; i < 64; i += 4)
        t[i][a] = in[(size_t)g * 65536 + (size_t)(d0 + i) * 256 + e0 + a];
    __syncthreads();
    for (int i = q; i < 64; i += 4)
        out[(size_t)g * 65536 + (size_t)(e0 + i) * 256 + d0 + a] = f2bf(t[a][i]);
}

// ---------------------------------------------------------------------------
// Instance norm on bf16 transposed buffer x[B][N][512], 3 passes.
// ---------------------------------------------------------------------------
__global__ __launch_bounds__(256) void in_stats1(
    const unsigned short* __restrict__ x, float* __restrict__ part, int N)
{
    int b = blockIdx.y, ch = blockIdx.x, tid = threadIdx.x;
    int nch = gridDim.x;
    float s0 = 0, q0 = 0, s1 = 0, q1 = 0;
    for (int r = 0; r < 256; ++r) {
        size_t base = ((size_t)b * N + ch * 256 + r) * 512;
        float v0 = bf2f(x[base + tid]);
        float v1 = bf2f(x[base + 256 + tid]);
        s0 += v0; q0 += v0 * v0; s1 += v1; q1 += v1 * v1;
    }
    size_t p = ((size_t)(b * nch + ch)) * 1024;
    part[p + tid] = s0;  part[p + 256 + tid] = q0;
    part[p + 512 + tid] = s1;  part[p + 768 + tid] = q1;
}

__global__ __launch_bounds__(512) void in_stats2(
    const float* __restrict__ part, float* __restrict__ mr, int N, int nch)
{
    int b = blockIdx.x, c = threadIdx.x;      // c in 0..511
    int half = c >> 8, cc = c & 255;
    float s = 0, q = 0;
    for (int ch = 0; ch < nch; ++ch) {
        size_t p = ((size_t)(b * nch + ch)) * 1024 + half * 512;
        s += part[p + cc];
        q += part[p + 256 + cc];
    }
    float m = s / N;
    float var = q / N - m * m;
    mr[(size_t)b * 1024 + c] = m;
    mr[(size_t)b * 1024 + 512 + c] = rsqrtf(var + 1e-5f);
}

__global__ __launch_bounds__(256) void in_apply(
    unsigned short* __restrict__ x, const float* __restrict__ mr, int N)
{
    int b = blockIdx.y, ch = blockIdx.x, tid = threadIdx.x;
    float m0 = mr[(size_t)b * 1024 + tid];
    float r0 = mr[(size_t)b * 1024 + 512 + tid];
    float m1 = mr[(size_t)b * 1024 + 256 + tid];
    float r1 = mr[(size_t)b * 1024 + 768 + tid];
    for (int r = 0; r < 256; ++r) {
        size_t base = ((size_t)b * N + ch * 256 + r) * 512;
        float v0 = (bf2f(x[base + tid]) - m0) * r0;
        x[base + tid] = f2bf(v0 > 0.f ? v0 : 0.f);
        float v1 = (bf2f(x[base + 256 + tid]) - m1) * r1;
        x[base + 256 + tid] = f2bf(v1 > 0.f ? v1 : 0.f);
    }
}

// ---------------------------------------------------------------------------
// Linear attention (fp32, unchanged math from round 1)
// ---------------------------------------------------------------------------
__global__ __launch_bounds__(256) void kv_partial_kernel(
    const float* __restrict__ kc, const float* __restrict__ vc,
    float* __restrict__ part, int M)
{
    const int s = blockIdx.x, h = blockIdx.y, b = blockIdx.z;
    const int chunk = M / KVS;
    const int m_begin = s * chunk;
    const int tid = threadIdx.x;
    const int ty = tid >> 4, tx = tid & 15;

    __shared__ float ke[64][65];
    __shared__ float ve[64][65];

    float acc[4][4] = {};
    float ksacc = 0.f;

    for (int mt = 0; mt < chunk; mt += 64) {
        #pragma unroll
        for (int i = 0; i < 16; ++i) {
            int e = tid + i * 256;
            int m = e & 63, d = e >> 6;
            size_t idx = ((size_t)b * 256 + d * 4 + h) * M + m_begin + mt + m;
            float kval = kc[idx];
            ke[d][m] = kval > 0.f ? kval + 1.0f : expf(kval);
            ve[d][m] = vc[idx];
        }
        __syncthreads();
        for (int mm = 0; mm < 64; ++mm) {
            float a_[4], b_[4];
            #pragma unroll
            for (int i = 0; i < 4; ++i) a_[i] = ke[ty * 4 + i][mm];
            #pragma unroll
            for (int j = 0; j < 4; ++j) b_[j] = ve[tx * 4 + j][mm];
            #pragma unroll
            for (int i = 0; i < 4; ++i)
                #pragma unroll
                for (int j = 0; j < 4; ++j)
                    acc[i][j] += a_[i] * b_[j];
        }
        if (tid < 64) {
            float t = 0.f;
            for (int mm = 0; mm < 64; ++mm) t += ke[tid][mm];
            ksacc += t;
        }
        __syncthreads();
    }

    float* pb_ = part + (size_t)((b * 4 + h) * KVS + s) * 4160;
    #pragma unroll
    for (int i = 0; i < 4; ++i)
        #pragma unroll
        for (int j = 0; j < 4; ++j)
            pb_[(ty * 4 + i) * 64 + tx * 4 + j] = acc[i][j];
    if (tid < 64) pb_[4096 + tid] = ksacc;
}

__global__ __launch_bounds__(256) void kv_reduce_kernel(
    const float* __restrict__ part, float* __restrict__ KV,
    float* __restrict__ ks)
{
    const int bh = blockIdx.x;
    const float* p0 = part + (size_t)bh * KVS * 4160;
    for (int idx = threadIdx.x; idx < 4096; idx += 256) {
        float t = 0.f;
        for (int s = 0; s < KVS; ++s) t += p0[(size_t)s * 4160 + idx];
        KV[(size_t)bh * 4096 + idx] = t;
    }
    if (threadIdx.x < 64) {
        float t = 0.f;
        for (int s = 0; s < KVS; ++s) t += p0[(size_t)s * 4160 + 4096 + threadIdx.x];
        ks[bh * 64 + threadIdx.x] = t;
    }
}

// out: bf16 transposed [B][N][256]
__global__ __launch_bounds__(256) void attn_apply_kernel(
    const float* __restrict__ qc, const float* __restrict__ KV,
    const float* __restrict__ ksum, unsigned short* __restrict__ outT, int N)
{
    const int h = blockIdx.y, b = blockIdx.z;
    const int m0 = blockIdx.x * 64;
    const int bh = b * 4 + h;
    const int tid = threadIdx.x;

    __shared__ float kvl[64][65];
    __shared__ float qe[64][65];
    __shared__ float ksl[64];

    #pragma unroll
    for (int i = 0; i < 16; ++i) {
        int e = tid + i * 256;
        int q = e & 63, d = e >> 6;
        kvl[d][q] = KV[(size_t)bh * 4096 + d * 64 + q];
    }
    if (tid < 64) ksl[tid] = ksum[bh * 64 + tid];
    #pragma unroll
    for (int i = 0; i < 16; ++i) {
        int e = tid + i * 256;
        int m = e & 63, d = e >> 6;
        float v = qc[((size_t)b * 256 + d * 4 + h) * N + m0 + m];
        qe[d][m] = v > 0.f ? v + 1.0f : expf(v);
    }
    __syncthreads();

    const int m = tid & 63;
    const int qg = tid >> 6;

    float den = 0.f;
    for (int d = 0; d < 64; ++d) den += qe[d][m] * ksl[d];
    float Z = 1.0f / (den + 1e-6f);

    size_t rowbase = ((size_t)b * N + m0 + m) * 256 + h;
    for (int qi = 0; qi < 16; ++qi) {
        int q = qg * 16 + qi;
        float v = 0.f;
        for (int d = 0; d < 64; ++d) v += qe[d][m] * kvl[d][q];
        outT[rowbase + q * 4] = f2bf(v * Z);
    }
}

// ---------------------------------------------------------------------------
// GAT fused scoring + aggregation (writes fp32 [c][n] state + bf16 [n][c])
// ---------------------------------------------------------------------------
__global__ __launch_bounds__(256) void gat_fuse_kernel(
    const float* __restrict__ Wh3t, const float* __restrict__ Wh2t,
    const float* __restrict__ avec, float* __restrict__ d3out,
    unsigned short* __restrict__ t_d3, int n3, int n1)
{
    const int n = blockIdx.x, b = blockIdx.y;
    const int tid = threadIdx.x;

    __shared__ float rows[9][256];
    __shared__ float redbuf[4];
    __shared__ float scores[10];
    __shared__ float attn[9];

    rows[0][tid] = Wh3t[((size_t)b * n3 + n) * 256 + tid];
    #pragma unroll
    for (int l = 1; l < 9; ++l)
        rows[l][tid] = Wh2t[((size_t)b * n1 + n * 8 + (l - 1)) * 256 + tid];
    __syncthreads();

    const float a1v = avec[tid];
    const float a2v = avec[256 + tid];

    for (int idx = 0; idx < 10; ++idx) {
        float p = (idx == 0) ? rows[0][tid] * a1v : rows[idx - 1][tid] * a2v;
        #pragma unroll
        for (int off = 32; off; off >>= 1) p += __shfl_down(p, off, 64);
        if ((tid & 63) == 0) redbuf[tid >> 6] = p;
        __syncthreads();
        if (tid == 0) scores[idx] = redbuf[0] + redbuf[1] + redbuf[2] + redbuf[3];
        __syncthreads();
    }

    if (tid == 0) {
        float s3 = scores[0];
        float e[9], mx = -1e30f;
        #pragma unroll
        for (int l = 0; l < 9; ++l) {
            float t = s3 + scores[l + 1];
            t = t > 0.f ? t : 0.2f * t;
            e[l] = t; mx = fmaxf(mx, t);
        }
        float sum = 0.f;
        #pragma unroll
        for (int l = 0; l < 9; ++l) { e[l] = expf(e[l] - mx); sum += e[l]; }
        #pragma unroll
        for (int l = 0; l < 9; ++l) attn[l] = e[l] / sum;
    }
    __syncthreads();

    float hv = 0.f;
    #pragma unroll
    for (int l = 0; l < 9; ++l) hv += attn[l] * rows[l][tid];
    hv = hv > 0.f ? hv : expf(hv) - 1.0f;
    d3out[((size_t)b * 256 + tid) * n3 + n] = hv;
    t_d3[((size_t)b * n3 + n) * 256 + tid] = f2bf(hv);
}

// ---------------------------------------------------------------------------
// host side
// ---------------------------------------------------------------------------
static void conv_mfma(hipStream_t s, const unsigned short* W,
                      const unsigned short* XA, int CA,
                      const unsigned short* XB, int C,
                      const float* bias, float* outF, unsigned short* outT,
                      int mode, int O, int N)
{
    dim3 g(N / 128, O / 128, BATCH);
    conv_mfma_kernel<<<g, 256, 0, s>>>(W, XA, CA, XB, C, bias, outF, outT, mode, O, N);
}

struct Bufs {
    float *Qb, *Kb, *Vb, *kvp, *KVb, *ksb, *part, *mr;
    unsigned short *AbT, *MbT, *HbT;
};

static void attn_prop2(hipStream_t s, const Bufs& w,
                       const unsigned short* Tx, int N,
                       const unsigned short* Tsrc, int M,
                       const unsigned short* wq, const unsigned short* wk,
                       const unsigned short* wv, const float* pb,
                       const unsigned short* wm, const float* mb,
                       const unsigned short* wm1, const float* m1b,
                       const unsigned short* wm2, const float* m2b,
                       float* Pstate)
{
    conv_mfma(s, wq, Tx,   256, nullptr, 256, pb,       w.Qb, nullptr, OM_F32N, 256, N);
    conv_mfma(s, wk, Tsrc, 256, nullptr, 256, pb + 256, w.Kb, nullptr, OM_F32N, 256, M);
    conv_mfma(s, wv, Tsrc, 256, nullptr, 256, pb + 512, w.Vb, nullptr, OM_F32N, 256, M);
    kv_partial_kernel<<<dim3(KVS, 4, BATCH), 256, 0, s>>>(w.Kb, w.Vb, w.kvp, M);
    kv_reduce_kernel<<<BATCH * 4, 256, 0, s>>>(w.kvp, w.KVb, w.ksb);
    attn_apply_kernel<<<dim3(N / 64, 4, BATCH), 256, 0, s>>>(w.Qb, w.KVb, w.ksb, w.AbT, N);
    conv_mfma(s, wm, w.AbT, 256, nullptr, 256, mb, nullptr, w.MbT, OM_BF16T, 256, N);
    conv_mfma(s, wm1, Tx, 256, w.MbT, 512, m1b, nullptr, w.HbT, OM_BF16T, 512, N);
    in_stats1<<<dim3(N / 256, BATCH), 256, 0, s>>>(w.HbT, w.part, N);
    in_stats2<<<BATCH, 512, 0, s>>>(w.part, w.mr, N, N / 256);
    in_apply<<<dim3(N / 256, BATCH), 256, 0, s>>>(w.HbT, w.mr, N);
    conv_mfma(s, wm2, w.HbT, 512, nullptr, 512, m2b, Pstate, nullptr, OM_F32N_ACC, 256, N);
}

extern "C" void kernel_launch(void* const* d_in, const int* in_sizes, int n_in,
                              void* d_out, int out_size, void* d_ws, size_t ws_size,
                              hipStream_t stream)
{
    const float* in_q  = (const float*)d_in[0];
    const float* in_d3 = (const float*)d_in[1];
    const float* in_d2 = (const float*)d_in[2];
    const float* gat_W = (const float*)d_in[3];
    const float* gat_a = (const float*)d_in[4];
    const float* pw    = (const float*)d_in[5];
    const float* pb    = (const float*)d_in[6];
    const float* mw    = (const float*)d_in[7];
    const float* mb    = (const float*)d_in[8];
    const float* m1w   = (const float*)d_in[9];
    const float* m1b   = (const float*)d_in[10];
    const float* m2w   = (const float*)d_in[11];
    const float* m2b   = (const float*)d_in[12];

    const size_t SZ_Q  = (size_t)BATCH * 256 * NQ;    // 8,388,608
    const size_t SZ_D3 = (size_t)BATCH * 256 * N3C;   // 4,194,304
    const size_t SZ_D2 = (size_t)BATCH * 256 * N1;    // 33,554,432

    float* P_Q  = (float*)d_out;
    float* P_D3 = P_Q + SZ_Q;

    float* w = (float*)d_ws;
    size_t off = 0;
    Bufs ws;
    ws.Qb  = w + off; off += SZ_Q;                       // fp32
    ws.Kb  = w + off; off += SZ_Q;
    ws.Vb  = w + off; off += SZ_Q;
    unsigned short* AbT = (unsigned short*)(w + off); off += SZ_Q / 2;   // bf16
    unsigned short* MbT = (unsigned short*)(w + off); off += SZ_Q / 2;
    unsigned short* HbT = (unsigned short*)(w + off); off += SZ_Q;       // [N][512] bf16
    // GAT overlay over [0 .. off): Wh2t fp32 (33.5M) + Wh3t fp32 (4.2M) <= 41.9M
    float* Wh2t = w;
    float* Wh3t = w + SZ_D2;
    ws.AbT = AbT; ws.MbT = MbT; ws.HbT = HbT;

    ws.kvp = w + off; off += (size_t)BATCH * 4 * KVS * 4160;
    ws.KVb = w + off; off += (size_t)BATCH * 4 * 4096;
    ws.ksb = w + off; off += (size_t)BATCH * 4 * 64;
    ws.part = w + off; off += (size_t)BATCH * 16 * 1024;
    ws.mr   = w + off; off += (size_t)BATCH * 1024;

    unsigned short* T_Q  = (unsigned short*)(w + off); off += SZ_Q / 2;
    unsigned short* T_D3 = (unsigned short*)(w + off); off += SZ_D3 / 2;
    unsigned short* T_D2 = (unsigned short*)(w + off); off += SZ_D2 / 2;

    unsigned short* WB = (unsigned short*)(w + off);
    unsigned short* wb_gat = WB;                       // 3 * 65536 (transposed)
    unsigned short* wb_pw  = wb_gat + 3 * 65536;       // 18 * 65536
    unsigned short* wb_mw  = wb_pw + 18 * 65536;       // 6 * 65536
    unsigned short* wb_m1  = wb_mw + 6 * 65536;        // 6 * 262144
    unsigned short* wb_m2  = wb_m1 + (size_t)6 * 262144; // 6 * 131072

    // ---- one-time conversions ----
    wtrans_cvt_kernel<<<dim3(4, 4, 3), 256, 0, stream>>>(gat_W, wb_gat);
    cvt_bf16_kernel<<<1024, 256, 0, stream>>>(pw,  wb_pw, (size_t)18 * 65536);
    cvt_bf16_kernel<<<1024, 256, 0, stream>>>(mw,  wb_mw, (size_t)6 * 65536);
    cvt_bf16_kernel<<<1024, 256, 0, stream>>>(m1w, wb_m1, (size_t)6 * 262144);
    cvt_bf16_kernel<<<1024, 256, 0, stream>>>(m2w, wb_m2, (size_t)6 * 131072);
    tcvt_kernel<<<dim3(NQ / 64, 4, BATCH), 256, 0, stream>>>(in_q,  T_Q,  256, NQ);
    tcvt_kernel<<<dim3(N3C / 64, 4, BATCH), 256, 0, stream>>>(in_d3, T_D3, 256, N3C);
    tcvt_kernel<<<dim3(N1 / 64, 4, BATCH), 256, 0, stream>>>(in_d2, T_D2, 256, N1);

    hipMemcpyAsync(P_Q,  in_q,  SZ_Q  * sizeof(float), hipMemcpyDeviceToDevice, stream);
    hipMemcpyAsync(P_D3, in_d3, SZ_D3 * sizeof(float), hipMemcpyDeviceToDevice, stream);

    int gi = 0, ai = 0;
    for (int L = 0; L < 9; ++L) {
        int kind = L % 3;
        if (kind == 0) {
            const unsigned short* Wg = wb_gat + (size_t)gi * 65536;
            const float* ag = gat_a + (size_t)gi * 512;
            conv_mfma(stream, Wg, T_D3, 256, nullptr, 256, nullptr, Wh3t, nullptr, OM_F32T, 256, N3C);
            conv_mfma(stream, Wg, T_D2, 256, nullptr, 256, nullptr, Wh2t, nullptr, OM_F32T, 256, N1);
            gat_fuse_kernel<<<dim3(N3C, BATCH), 256, 0, stream>>>(
                Wh3t, Wh2t, ag, P_D3, T_D3, N3C, N1);
            gi++;
        } else {
            bool cross = (kind == 2);
            const unsigned short* wq = wb_pw + (size_t)(ai * 3 + 0) * 65536;
            const unsigned short* wk = wb_pw + (size_t)(ai * 3 + 1) * 65536;
            const unsigned short* wv = wb_pw + (size_t)(ai * 3 + 2) * 65536;
            const float* pbi  = pb  + (size_t)ai * 3 * 256;
            const unsigned short* wmi = wb_mw + (size_t)ai * 65536;
            const float* mbi  = mb  + (size_t)ai * 256;
            const unsigned short* wm1i = wb_m1 + (size_t)ai * 262144;
            const float* m1bi = m1b + (size_t)ai * 512;
            const unsigned short* wm2i = wb_m2 + (size_t)ai * 131072;
            const float* m2bi = m2b + (size_t)ai * 256;

            attn_prop2(stream, ws, T_Q, NQ,
                       cross ? T_D3 : T_Q, cross ? N3C : NQ,
                       wq, wk, wv, pbi, wmi, mbi, wm1i, m1bi, wm2i, m2bi, P_Q);
            attn_prop2(stream, ws, T_D3, N3C,
                       cross ? T_Q : T_D3, cross ? NQ : N3C,
                       wq, wk, wv, pbi, wmi, mbi, wm1i, m1bi, wm2i, m2bi, P_D3);
            // refresh bf16 transposed states
            tcvt_kernel<<<dim3(NQ / 64, 4, BATCH), 256, 0, stream>>>(P_Q,  T_Q,  256, NQ);
            tcvt_kernel<<<dim3(N3C / 64, 4, BATCH), 256, 0, stream>>>(P_D3, T_D3, 256, N3C);
            ai++;
        }
    }
    (void)in_sizes; (void)n_in; (void)out_size; (void)ws_size;
}

// Round 4
// 3451.089 us; speedup vs baseline: 2.9143x; 1.0520x over previous
//
#include <hip/hip_runtime.h>
#include <cstddef>
#include <cstdint>

// ---------------------------------------------------------------------------
// AttentionalGNN: 3 x (GAT, self-attn, cross-attn)
// B=8, D=256, NQ=4096, N3=2048, N1=16384, heads=4, dim=64
// Round 4: round-3 design with GAT workspace overlay fix
//   (Wh2T spans Qf + half of KVf; Wh3T now lives in AttT, not KVf).
// ---------------------------------------------------------------------------

#define NQ 4096
#define N3C 2048
#define N1 16384
#define BATCH 8
#define KVS 16

typedef __attribute__((ext_vector_type(8))) short bf16x8;
typedef __attribute__((ext_vector_type(4))) float f32x4;

__device__ __forceinline__ unsigned short f2bf(float f) {
    union { float f; unsigned u; } v; v.f = f;
    unsigned r = v.u + 0x7fffu + ((v.u >> 16) & 1u);
    return (unsigned short)(r >> 16);
}
__device__ __forceinline__ float bf2f(unsigned short h) {
    union { unsigned u; float f; } v; v.u = ((unsigned)h) << 16; return v.f;
}

__device__ __forceinline__ void gload_lds16(const void* g, void* l) {
    __builtin_amdgcn_global_load_lds(
        (const __attribute__((address_space(1))) unsigned int*)g,
        (__attribute__((address_space(3))) unsigned int*)l, 16, 0, 0);
}

#define OM_F32N   0
#define OM_BF16T  1
#define OM_ACC_T  2
#define OM_BF16N  3

// ---------------------------------------------------------------------------
// MFMA GEMM: out(o,n) = bias[o] + sum_c W[o][c] * X[n][c]   (per batch b)
// ---------------------------------------------------------------------------
__global__ __launch_bounds__(256) void conv_mfma_kernel(
    const unsigned short* __restrict__ W,
    const unsigned short* __restrict__ XA, int CA,
    const unsigned short* __restrict__ XB,
    int C,
    const float* __restrict__ bias,
    float* __restrict__ outF,
    unsigned short* __restrict__ outT,
    int outMode, int O, int ldo, int N)
{
    const int b  = blockIdx.z;
    const int o0 = blockIdx.y * 128;
    const int n0 = blockIdx.x * 128;
    const int tid = threadIdx.x;
    const int wid = tid >> 6, lane = tid & 63;
    const int wr = wid >> 1, wc = wid & 1;
    const int lr = lane & 15, kg = lane >> 4;
    const int CB = C - CA;

    __shared__ short As[128 * 32];
    __shared__ short Bs[128 * 32];

    f32x4 acc[4][4] = {};

    for (int c0 = 0; c0 < C; c0 += 32) {
        #pragma unroll
        for (int it = 0; it < 2; ++it) {
            int chunk = it * 256 + tid;
            int row = chunk >> 2;
            int ksw = (chunk & 3) ^ (row & 3);
            gload_lds16(W + (size_t)(o0 + row) * C + c0 + ksw * 8,
                        (char*)As + it * 4096 + wid * 1024);
        }
        #pragma unroll
        for (int it = 0; it < 2; ++it) {
            int chunk = it * 256 + tid;
            int row = chunk >> 2;
            int ksw = (chunk & 3) ^ (row & 3);
            int cc = c0 + ksw * 8;
            const unsigned short* src =
                (cc < CA) ? XA + ((size_t)b * N + n0 + row) * CA + cc
                          : XB + ((size_t)b * N + n0 + row) * CB + (cc - CA);
            gload_lds16(src, (char*)Bs + it * 4096 + wid * 1024);
        }
        __syncthreads();

        bf16x8 af[4], bfr[4];
        #pragma unroll
        for (int m = 0; m < 4; ++m) {
            int row = wr * 64 + m * 16 + lr;
            af[m] = *(const bf16x8*)((const char*)As + row * 64 + ((kg ^ (row & 3)) * 16));
        }
        #pragma unroll
        for (int n = 0; n < 4; ++n) {
            int row = wc * 64 + n * 16 + lr;
            bfr[n] = *(const bf16x8*)((const char*)Bs + row * 64 + ((kg ^ (row & 3)) * 16));
        }
        #pragma unroll
        for (int m = 0; m < 4; ++m)
            #pragma unroll
            for (int n = 0; n < 4; ++n)
                acc[m][n] = __builtin_amdgcn_mfma_f32_16x16x32_bf16(
                    af[m], bfr[n], acc[m][n], 0, 0, 0);
        __syncthreads();
    }

    // C/D frag: col = lane&15, row = (lane>>4)*4 + r
    #pragma unroll
    for (int m = 0; m < 4; ++m) {
        const int ob = o0 + wr * 64 + m * 16 + (lane >> 4) * 4;
        float bv[4] = {0.f, 0.f, 0.f, 0.f};
        if (bias) {
            #pragma unroll
            for (int r = 0; r < 4; ++r) bv[r] = bias[ob + r];
        }
        #pragma unroll
        for (int n = 0; n < 4; ++n) {
            const int col = n0 + wc * 64 + n * 16 + lr;
            f32x4 v = acc[m][n];
            #pragma unroll
            for (int r = 0; r < 4; ++r) v[r] += bv[r];
            if (outMode == OM_F32N) {
                #pragma unroll
                for (int r = 0; r < 4; ++r)
                    outF[((size_t)b * O + ob + r) * N + col] = v[r];
            } else if (outMode == OM_BF16T) {
                unsigned p0 = ((unsigned)f2bf(v[1]) << 16) | f2bf(v[0]);
                unsigned p1 = ((unsigned)f2bf(v[3]) << 16) | f2bf(v[2]);
                *(uint2*)(outT + ((size_t)b * N + col) * ldo + ob) = make_uint2(p0, p1);
            } else if (outMode == OM_ACC_T) {
                #pragma unroll
                for (int r = 0; r < 4; ++r) {
                    float nv = outF[((size_t)b * O + ob + r) * N + col] + v[r];
                    outF[((size_t)b * O + ob + r) * N + col] = nv;
                    v[r] = nv;
                }
                unsigned p0 = ((unsigned)f2bf(v[1]) << 16) | f2bf(v[0]);
                unsigned p1 = ((unsigned)f2bf(v[3]) << 16) | f2bf(v[2]);
                *(uint2*)(outT + ((size_t)b * N + col) * ldo + ob) = make_uint2(p0, p1);
            } else {  // OM_BF16N (weight-build, b==0)
                #pragma unroll
                for (int r = 0; r < 4; ++r)
                    outT[(size_t)(ob + r) * ldo + col] = f2bf(v[r]);
            }
        }
    }
}

// ---------------------------------------------------------------------------
// fp32 [B][C][N] -> bf16 [B][N][C] transpose-convert
// ---------------------------------------------------------------------------
__global__ __launch_bounds__(256) void tcvt_kernel(
    const float* __restrict__ in, unsigned short* __restrict__ out,
    int C, int N)
{
    int b = blockIdx.z;
    int n0 = blockIdx.x * 64, c0 = blockIdx.y * 64;
    __shared__ float t[64][65];
    int a = threadIdx.x & 63, q = threadIdx.x >> 6;
    for (int i = q; i < 64; i += 4)
        t[i][a] = in[((size_t)b * C + c0 + i) * N + n0 + a];
    __syncthreads();
    for (int i = q; i < 64; i += 4)
        out[((size_t)b * N + n0 + i) * C + c0 + a] = f2bf(t[a][i]);
}

__global__ __launch_bounds__(256) void cvt_bf16_kernel(
    const float* __restrict__ in, unsigned short* __restrict__ out, size_t n)
{
    size_t i = (size_t)blockIdx.x * 256 + threadIdx.x;
    size_t stride = (size_t)gridDim.x * 256;
    for (; i < n; i += stride) out[i] = f2bf(in[i]);
}

// fp32 [Z][D][D] -> bf16 transposed [Z][D][D]: out[z][i][j] = in[z][j][i]
__global__ __launch_bounds__(256) void wtrans_cvt_kernel(
    const float* __restrict__ in, unsigned short* __restrict__ out, int D)
{
    int z = blockIdx.z;
    int i0 = blockIdx.x * 64, j0 = blockIdx.y * 64;
    __shared__ float t[64][65];
    int a = threadIdx.x & 63, q = threadIdx.x >> 6;
    const float* src = in + (size_t)z * D * D;
    unsigned short* dst = out + (size_t)z * D * D;
    for (int i = q; i < 64; i += 4)
        t[i][a] = src[(size_t)(j0 + i) * D + i0 + a];
    __syncthreads();
    for (int i = q; i < 64; i += 4)
        dst[(size_t)(i0 + i) * D + j0 + a] = f2bf(t[a][i]);
}

// wmT with h-major permutation: out[ai][n'][c] = mw[ai][c][perm(n')],
// perm(h*64+q) = q*4+h.  grid (256, 6), 256 thr.
__global__ __launch_bounds__(256) void wmt_perm_kernel(
    const float* __restrict__ mw, unsigned short* __restrict__ out)
{
    int ai = blockIdx.y, np = blockIdx.x, c = threadIdx.x;
    int h = np >> 6, q = np & 63;
    int orig = q * 4 + h;
    out[(size_t)ai * 65536 + (size_t)np * 256 + c] =
        f2bf(mw[(size_t)ai * 65536 + (size_t)c * 256 + orig]);
}

// split m1w into bf16 A-half (into combined [512][512], cols 0-255) and
// B-half [512][256].  grid (512, 6), 256 thr.
__global__ __launch_bounds__(256) void ext_m1_kernel(
    const float* __restrict__ m1w, unsigned short* __restrict__ m1c,
    unsigned short* __restrict__ w1b)
{
    int ai = blockIdx.y, o = blockIdx.x, c = threadIdx.x;
    const float* src = m1w + (size_t)ai * 262144 + (size_t)o * 512;
    m1c[(size_t)ai * 262144 + (size_t)o * 512 + c] = f2bf(src[c]);
    w1b[(size_t)ai * 131072 + (size_t)o * 256 + c] = f2bf(src[256 + c]);
}

// bfold[ai][o] = m1b[ai][o] + sum_c m1w[ai][o][256+c] * mb[ai][c].  grid (2,6)
__global__ __launch_bounds__(256) void bias_fold_kernel(
    const float* __restrict__ m1w, const float* __restrict__ m1b,
    const float* __restrict__ mb, float* __restrict__ bf)
{
    int ai = blockIdx.y;
    int o = blockIdx.x * 256 + threadIdx.x;
    const float* wrow = m1w + (size_t)ai * 262144 + (size_t)o * 512 + 256;
    const float* mbp = mb + (size_t)ai * 256;
    float s = m1b[(size_t)ai * 512 + o];
    for (int c = 0; c < 256; ++c) s += wrow[c] * mbp[c];
    bf[(size_t)ai * 512 + o] = s;
}

// ---------------------------------------------------------------------------
// Instance norm on bf16 [B][N][512], 3 passes.
// ---------------------------------------------------------------------------
__global__ __launch_bounds__(256) void in_stats1(
    const unsigned short* __restrict__ x, float* __restrict__ part, int N)
{
    int b = blockIdx.y, ch = blockIdx.x, tid = threadIdx.x;
    int nch = gridDim.x;
    float s0 = 0, q0 = 0, s1 = 0, q1 = 0;
    for (int r = 0; r < 256; ++r) {
        size_t base = ((size_t)b * N + ch * 256 + r) * 512;
        float v0 = bf2f(x[base + tid]);
        float v1 = bf2f(x[base + 256 + tid]);
        s0 += v0; q0 += v0 * v0; s1 += v1; q1 += v1 * v1;
    }
    size_t p = ((size_t)(b * nch + ch)) * 1024;
    part[p + tid] = s0;  part[p + 256 + tid] = q0;
    part[p + 512 + tid] = s1;  part[p + 768 + tid] = q1;
}

__global__ __launch_bounds__(512) void in_stats2(
    const float* __restrict__ part, float* __restrict__ mr, int N, int nch)
{
    int b = blockIdx.x, c = threadIdx.x;
    int half = c >> 8, cc = c & 255;
    float s = 0, q = 0;
    for (int ch = 0; ch < nch; ++ch) {
        size_t p = ((size_t)(b * nch + ch)) * 1024 + half * 512;
        s += part[p + cc];
        q += part[p + 256 + cc];
    }
    float m = s / N;
    float var = q / N - m * m;
    mr[(size_t)b * 1024 + c] = m;
    mr[(size_t)b * 1024 + 512 + c] = rsqrtf(var + 1e-5f);
}

__global__ __launch_bounds__(256) void in_apply(
    unsigned short* __restrict__ x, const float* __restrict__ mr, int N)
{
    int b = blockIdx.y, ch = blockIdx.x, tid = threadIdx.x;
    float m0 = mr[(size_t)b * 1024 + tid];
    float r0 = mr[(size_t)b * 1024 + 512 + tid];
    float m1 = mr[(size_t)b * 1024 + 256 + tid];
    float r1 = mr[(size_t)b * 1024 + 768 + tid];
    for (int r = 0; r < 256; ++r) {
        size_t base = ((size_t)b * N + ch * 256 + r) * 512;
        float v0 = (bf2f(x[base + tid]) - m0) * r0;
        x[base + tid] = f2bf(v0 > 0.f ? v0 : 0.f);
        float v1 = (bf2f(x[base + 256 + tid]) - m1) * r1;
        x[base + 256 + tid] = f2bf(v1 > 0.f ? v1 : 0.f);
    }
}

// ---------------------------------------------------------------------------
// Linear attention.  KVf fp32 [B][512][M]: k rows 0-255, v rows 256-511.
// ---------------------------------------------------------------------------
__global__ __launch_bounds__(256) void kv_partial_kernel(
    const float* __restrict__ kvf, float* __restrict__ part, int M)
{
    const int s = blockIdx.x, h = blockIdx.y, b = blockIdx.z;
    const int chunk = M / KVS;
    const int m_begin = s * chunk;
    const int tid = threadIdx.x;
    const int ty = tid >> 4, tx = tid & 15;

    __shared__ float ke[64][65];
    __shared__ float ve[64][65];

    float acc[4][4] = {};
    float ksacc = 0.f;

    for (int mt = 0; mt < chunk; mt += 64) {
        #pragma unroll
        for (int i = 0; i < 16; ++i) {
            int e = tid + i * 256;
            int m = e & 63, d = e >> 6;
            size_t idx = ((size_t)b * 512 + d * 4 + h) * M + m_begin + mt + m;
            float kval = kvf[idx];
            ke[d][m] = kval > 0.f ? kval + 1.0f : __expf(kval);
            ve[d][m] = kvf[idx + (size_t)256 * M];
        }
        __syncthreads();
        for (int mm = 0; mm < 64; ++mm) {
            float a_[4], b_[4];
            #pragma unroll
            for (int i = 0; i < 4; ++i) a_[i] = ke[ty * 4 + i][mm];
            #pragma unroll
            for (int j = 0; j < 4; ++j) b_[j] = ve[tx * 4 + j][mm];
            #pragma unroll
            for (int i = 0; i < 4; ++i)
                #pragma unroll
                for (int j = 0; j < 4; ++j)
                    acc[i][j] += a_[i] * b_[j];
        }
        if (tid < 64) {
            float t = 0.f;
            for (int mm = 0; mm < 64; ++mm) t += ke[tid][mm];
            ksacc += t;
        }
        __syncthreads();
    }

    float* pb_ = part + (size_t)((b * 4 + h) * KVS + s) * 4160;
    #pragma unroll
    for (int i = 0; i < 4; ++i)
        #pragma unroll
        for (int j = 0; j < 4; ++j)
            pb_[(ty * 4 + i) * 64 + tx * 4 + j] = acc[i][j];
    if (tid < 64) pb_[4096 + tid] = ksacc;
}

__global__ __launch_bounds__(256) void kv_reduce_kernel(
    const float* __restrict__ part, float* __restrict__ KV,
    float* __restrict__ ks)
{
    const int bh = blockIdx.x;
    const float* p0 = part + (size_t)bh * KVS * 4160;
    for (int idx = threadIdx.x; idx < 4096; idx += 256) {
        float t = 0.f;
        for (int s = 0; s < KVS; ++s) t += p0[(size_t)s * 4160 + idx];
        KV[(size_t)bh * 4096 + idx] = t;
    }
    if (threadIdx.x < 64) {
        float t = 0.f;
        for (int s = 0; s < KVS; ++s) t += p0[(size_t)s * 4160 + 4096 + threadIdx.x];
        ks[bh * 64 + threadIdx.x] = t;
    }
}

// out: bf16 [B][N][256] with h-major channel order ch' = h*64 + q
__global__ __launch_bounds__(256) void attn_apply_kernel(
    const float* __restrict__ qc, const float* __restrict__ KV,
    const float* __restrict__ ksum, unsigned short* __restrict__ outT, int N)
{
    const int h = blockIdx.y, b = blockIdx.z;
    const int m0 = blockIdx.x * 64;
    const int bh = b * 4 + h;
    const int tid = threadIdx.x;

    __shared__ float kvl[64][65];
    __shared__ float qe[64][65];
    __shared__ float ksl[64];

    #pragma unroll
    for (int i = 0; i < 16; ++i) {
        int e = tid + i * 256;
        int q = e & 63, d = e >> 6;
        kvl[d][q] = KV[(size_t)bh * 4096 + d * 64 + q];
    }
    if (tid < 64) ksl[tid] = ksum[bh * 64 + tid];
    #pragma unroll
    for (int i = 0; i < 16; ++i) {
        int e = tid + i * 256;
        int m = e & 63, d = e >> 6;
        float v = qc[((size_t)b * 256 + d * 4 + h) * N + m0 + m];
        qe[d][m] = v > 0.f ? v + 1.0f : __expf(v);
    }
    __syncthreads();

    const int m = tid & 63;
    const int qg = tid >> 6;

    float den = 0.f;
    for (int d = 0; d < 64; ++d) den += qe[d][m] * ksl[d];
    float Z = 1.0f / (den + 1e-6f);

    unsigned pk[8];
    #pragma unroll
    for (int qp = 0; qp < 8; ++qp) {
        int q0 = qg * 16 + qp * 2;
        float v0 = 0.f, v1 = 0.f;
        for (int d = 0; d < 64; ++d) {
            float qv = qe[d][m];
            v0 += qv * kvl[d][q0];
            v1 += qv * kvl[d][q0 + 1];
        }
        pk[qp] = ((unsigned)f2bf(v1 * Z) << 16) | f2bf(v0 * Z);
    }
    unsigned short* dst = outT + ((size_t)b * N + m0 + m) * 256 + h * 64 + qg * 16;
    *(uint4*)dst = make_uint4(pk[0], pk[1], pk[2], pk[3]);
    *(uint4*)(dst + 8) = make_uint4(pk[4], pk[5], pk[6], pk[7]);
}

// ---------------------------------------------------------------------------
// GAT: wave-per-node, shuffle reductions, LDS transpose for fp32 state write.
// Wh3T/Wh2T bf16 [b][n][256].  Block: 4 waves x 4 nodes = 16 nodes.
// ---------------------------------------------------------------------------
__global__ __launch_bounds__(256) void gat_fuse_kernel(
    const unsigned short* __restrict__ Wh3T,
    const unsigned short* __restrict__ Wh2T,
    const float* __restrict__ avec,
    float* __restrict__ d3out, unsigned short* __restrict__ t_d3,
    int n3, int n1)
{
    const int b = blockIdx.y;
    const int n0 = blockIdx.x * 16;
    const int wv = threadIdx.x >> 6, lane = threadIdx.x & 63;
    __shared__ float hbuf[16][256];

    float a1[4], a2[4];
    #pragma unroll
    for (int r = 0; r < 4; ++r) {
        a1[r] = avec[lane + 64 * r];
        a2[r] = avec[256 + lane + 64 * r];
    }

    for (int i = 0; i < 4; ++i) {
        int nl = wv * 4 + i;
        int n = n0 + nl;
        float rows[9][4];
        const unsigned short* p3 = Wh3T + ((size_t)b * n3 + n) * 256;
        #pragma unroll
        for (int r = 0; r < 4; ++r) rows[0][r] = bf2f(p3[lane + 64 * r]);
        #pragma unroll
        for (int l = 1; l < 9; ++l) {
            const unsigned short* p2 = Wh2T + ((size_t)b * n1 + (size_t)n * 8 + (l - 1)) * 256;
            #pragma unroll
            for (int r = 0; r < 4; ++r) rows[l][r] = bf2f(p2[lane + 64 * r]);
        }

        float part[10];
        {
            float s = 0.f;
            #pragma unroll
            for (int r = 0; r < 4; ++r) s += rows[0][r] * a1[r];
            part[0] = s;
        }
        #pragma unroll
        for (int l = 0; l < 9; ++l) {
            float s = 0.f;
            #pragma unroll
            for (int r = 0; r < 4; ++r) s += rows[l][r] * a2[r];
            part[1 + l] = s;
        }
        #pragma unroll
        for (int msk = 1; msk < 64; msk <<= 1)
            #pragma unroll
            for (int j = 0; j < 10; ++j)
                part[j] += __shfl_xor(part[j], msk, 64);

        float s3 = part[0];
        float e[9], mx = -1e30f;
        #pragma unroll
        for (int l = 0; l < 9; ++l) {
            float t = s3 + part[1 + l];
            t = t > 0.f ? t : 0.2f * t;
            e[l] = t; mx = fmaxf(mx, t);
        }
        float sum = 0.f;
        #pragma unroll
        for (int l = 0; l < 9; ++l) { e[l] = __expf(e[l] - mx); sum += e[l]; }
        float inv = 1.0f / sum;
        #pragma unroll
        for (int r = 0; r < 4; ++r) {
            float t = 0.f;
            #pragma unroll
            for (int l = 0; l < 9; ++l) t += e[l] * rows[l][r];
            t *= inv;
            t = t > 0.f ? t : __expf(t) - 1.0f;  // elu
            hbuf[nl][lane + 64 * r] = t;
            t_d3[((size_t)b * n3 + n) * 256 + lane + 64 * r] = f2bf(t);
        }
    }
    __syncthreads();
    const int c = threadIdx.x;
    float* dst = d3out + ((size_t)b * 256 + c) * n3 + n0;
    #pragma unroll
    for (int g = 0; g < 4; ++g) {
        f32x4 v;
        #pragma unroll
        for (int k = 0; k < 4; ++k) v[k] = hbuf[g * 4 + k][c];
        *(f32x4*)(dst + g * 4) = v;
    }
}

// ---------------------------------------------------------------------------
// host side
// ---------------------------------------------------------------------------
static void conv_mfma(hipStream_t s, const unsigned short* W,
                      const unsigned short* XA, int CA,
                      const unsigned short* XB, int C,
                      const float* bias, float* outF, unsigned short* outT,
                      int mode, int O, int ldo, int N, int nb)
{
    dim3 g(N / 128, O / 128, nb);
    conv_mfma_kernel<<<g, 256, 0, s>>>(W, XA, CA, XB, C, bias, outF, outT,
                                       mode, O, ldo, N);
}

struct Bufs {
    float *Qf, *KVf, *kvp, *KVb, *ksb, *part, *mr;
    unsigned short *AttT, *HbT;
};

static void attn_prop3(hipStream_t s, const Bufs& w,
                       const unsigned short* Tx, int N,
                       const unsigned short* Tsrc, int M,
                       const unsigned short* wqkv, const float* pbi,
                       const unsigned short* wm1c, const float* bfold,
                       const unsigned short* wm2, const float* m2b,
                       float* Pstate, unsigned short* Tstage)
{
    conv_mfma(s, wqkv, Tx, 256, nullptr, 256, pbi, w.Qf, nullptr,
              OM_F32N, 256, 0, N, BATCH);
    conv_mfma(s, wqkv + 65536, Tsrc, 256, nullptr, 256, pbi + 256, w.KVf, nullptr,
              OM_F32N, 512, 0, M, BATCH);
    kv_partial_kernel<<<dim3(KVS, 4, BATCH), 256, 0, s>>>(w.KVf, w.kvp, M);
    kv_reduce_kernel<<<BATCH * 4, 256, 0, s>>>(w.kvp, w.KVb, w.ksb);
    attn_apply_kernel<<<dim3(N / 64, 4, BATCH), 256, 0, s>>>(w.Qf, w.KVb, w.ksb, w.AttT, N);
    conv_mfma(s, wm1c, Tx, 256, w.AttT, 512, bfold, nullptr, w.HbT,
              OM_BF16T, 512, 512, N, BATCH);
    in_stats1<<<dim3(N / 256, BATCH), 256, 0, s>>>(w.HbT, w.part, N);
    in_stats2<<<BATCH, 512, 0, s>>>(w.part, w.mr, N, N / 256);
    in_apply<<<dim3(N / 256, BATCH), 256, 0, s>>>(w.HbT, w.mr, N);
    conv_mfma(s, wm2, w.HbT, 512, nullptr, 512, m2b, Pstate, Tstage,
              OM_ACC_T, 256, 256, N, BATCH);
}

extern "C" void kernel_launch(void* const* d_in, const int* in_sizes, int n_in,
                              void* d_out, int out_size, void* d_ws, size_t ws_size,
                              hipStream_t stream)
{
    const float* in_q  = (const float*)d_in[0];
    const float* in_d3 = (const float*)d_in[1];
    const float* in_d2 = (const float*)d_in[2];
    const float* gat_W = (const float*)d_in[3];
    const float* gat_a = (const float*)d_in[4];
    const float* pw    = (const float*)d_in[5];
    const float* pb    = (const float*)d_in[6];
    const float* mw    = (const float*)d_in[7];
    const float* mb    = (const float*)d_in[8];
    const float* m1w   = (const float*)d_in[9];
    const float* m1b   = (const float*)d_in[10];
    const float* m2w   = (const float*)d_in[11];
    const float* m2b   = (const float*)d_in[12];

    const size_t SZ_Q  = (size_t)BATCH * 256 * NQ;
    const size_t SZ_D3 = (size_t)BATCH * 256 * N3C;
    const size_t SZ_D2 = (size_t)BATCH * 256 * N1;

    float* P_Q  = (float*)d_out;
    float* P_D3 = P_Q + SZ_Q;

    float* w = (float*)d_ws;
    size_t off = 0;
    Bufs ws;
    ws.Qf  = w + off; off += SZ_Q;                       // 33.5 MB
    ws.KVf = w + off; off += (size_t)BATCH * 512 * NQ;   // 67 MB
    ws.AttT = (unsigned short*)(w + off); off += SZ_Q / 2;  // 16.7 MB
    ws.HbT  = (unsigned short*)(w + off); off += SZ_Q;      // 33.5 MB
    ws.kvp = w + off; off += (size_t)BATCH * 4 * KVS * 4160;
    ws.KVb = w + off; off += (size_t)BATCH * 4 * 4096;
    ws.ksb = w + off; off += (size_t)BATCH * 4 * 64;
    ws.part = w + off; off += (size_t)BATCH * 16 * 1024;
    ws.mr   = w + off; off += (size_t)BATCH * 1024;
    unsigned short* TQa  = (unsigned short*)(w + off); off += SZ_Q / 2;
    unsigned short* TQb  = (unsigned short*)(w + off); off += SZ_Q / 2;
    unsigned short* TD3a = (unsigned short*)(w + off); off += SZ_D3 / 2;
    unsigned short* TD3b = (unsigned short*)(w + off); off += SZ_D3 / 2;
    unsigned short* TD2  = (unsigned short*)(w + off); off += SZ_D2 / 2;
    unsigned short* wb_pw  = (unsigned short*)(w + off); off += (size_t)18 * 65536 / 2;
    unsigned short* wb_gat = (unsigned short*)(w + off); off += (size_t)3 * 65536 / 2;
    unsigned short* wb_wmT = (unsigned short*)(w + off); off += (size_t)6 * 65536 / 2;
    unsigned short* wb_m1c = (unsigned short*)(w + off); off += (size_t)6 * 262144 / 2;
    unsigned short* wb_w1b = (unsigned short*)(w + off); off += (size_t)6 * 131072 / 2;
    unsigned short* wb_m2  = (unsigned short*)(w + off); off += (size_t)6 * 131072 / 2;
    float* bfold = w + off; off += 6 * 512;

    // GAT overlays (all regions unused during GAT):
    //   Wh2T bf16 needs 67 MB  -> spans Qf (33.5 MB) + first half of KVf.
    //   Wh3T bf16 needs 8.4 MB -> lives in AttT (16.7 MB).  NO overlap.
    unsigned short* Wh2T = (unsigned short*)ws.Qf;
    unsigned short* Wh3T = ws.AttT;

    // ---- setup (per call, deterministic) ----
    cvt_bf16_kernel<<<1024, 256, 0, stream>>>(pw, wb_pw, (size_t)18 * 65536);
    wtrans_cvt_kernel<<<dim3(4, 4, 3), 256, 0, stream>>>(gat_W, wb_gat, 256);
    wmt_perm_kernel<<<dim3(256, 6), 256, 0, stream>>>(mw, wb_wmT);
    ext_m1_kernel<<<dim3(512, 6), 256, 0, stream>>>(m1w, wb_m1c, wb_w1b);
    cvt_bf16_kernel<<<1024, 256, 0, stream>>>(m2w, wb_m2, (size_t)6 * 131072);
    bias_fold_kernel<<<dim3(2, 6), 256, 0, stream>>>(m1w, m1b, mb, bfold);
    for (int ai = 0; ai < 6; ++ai)   // Wc = W1b @ Wm  (permuted cols), bf16
        conv_mfma(stream, wb_w1b + (size_t)ai * 131072,
                  wb_wmT + (size_t)ai * 65536, 256, nullptr, 256,
                  nullptr, nullptr, wb_m1c + (size_t)ai * 262144 + 256,
                  OM_BF16N, 512, 512, 256, 1);

    tcvt_kernel<<<dim3(NQ / 64, 4, BATCH), 256, 0, stream>>>(in_q,  TQa,  256, NQ);
    tcvt_kernel<<<dim3(N3C / 64, 4, BATCH), 256, 0, stream>>>(in_d3, TD3a, 256, N3C);
    tcvt_kernel<<<dim3(N1 / 64, 4, BATCH), 256, 0, stream>>>(in_d2, TD2,  256, N1);

    hipMemcpyAsync(P_Q,  in_q,  SZ_Q  * sizeof(float), hipMemcpyDeviceToDevice, stream);
    hipMemcpyAsync(P_D3, in_d3, SZ_D3 * sizeof(float), hipMemcpyDeviceToDevice, stream);

    unsigned short *TQ = TQa, *TQs = TQb, *TD3 = TD3a, *TD3s = TD3b;

    int gi = 0, ai = 0;
    for (int L = 0; L < 9; ++L) {
        int kind = L % 3;
        if (kind == 0) {
            conv_mfma(stream, wb_gat + (size_t)gi * 65536, TD3, 256, nullptr, 256,
                      nullptr, nullptr, Wh3T, OM_BF16T, 256, 256, N3C, BATCH);
            conv_mfma(stream, wb_gat + (size_t)gi * 65536, TD2, 256, nullptr, 256,
                      nullptr, nullptr, Wh2T, OM_BF16T, 256, 256, N1, BATCH);
            gat_fuse_kernel<<<dim3(N3C / 16, BATCH), 256, 0, stream>>>(
                Wh3T, Wh2T, gat_a + (size_t)gi * 512, P_D3, TD3, N3C, N1);
            gi++;
        } else {
            bool cross = (kind == 2);
            const unsigned short* wqkv = wb_pw + (size_t)ai * 3 * 65536;
            const float* pbi = pb + (size_t)ai * 768;
            const unsigned short* wm1c = wb_m1c + (size_t)ai * 262144;
            const float* bfi = bfold + (size_t)ai * 512;
            const unsigned short* wm2 = wb_m2 + (size_t)ai * 131072;
            const float* m2bi = m2b + (size_t)ai * 256;

            attn_prop3(stream, ws, TQ, NQ,
                       cross ? TD3 : TQ, cross ? N3C : NQ,
                       wqkv, pbi, wm1c, bfi, wm2, m2bi, P_Q, TQs);
            attn_prop3(stream, ws, TD3, N3C,
                       cross ? TQ : TD3, cross ? NQ : N3C,
                       wqkv, pbi, wm1c, bfi, wm2, m2bi, P_D3, TD3s);
            unsigned short* t;
            t = TQ;  TQ  = TQs;  TQs  = t;
            t = TD3; TD3 = TD3s; TD3s = t;
            ai++;
        }
    }
    (void)in_sizes; (void)n_in; (void)out_size; (void)ws_size;
}